// Round 4
// baseline (117.985 us; speedup 1.0000x reference)
//
#include <hip/hip_runtime.h>

// Problem constants (setup_inputs: [16, 3, 512, 512] fp32)
#define HW      262144      // 512*512 (power of two: 2^18)
#define HW_LOG2 18
#define NVEC    1048576     // 16*512*512/4  (float4-vectorized pixels)
#define CH      HW          // channel stride (elements)
#define BSTRIDE (3*HW)      // batch stride (elements)
#define NELEM_INV (1.0f / 12582912.0f)   // 1 / (16*3*512*512)

#define GRID1   2048
#define BLOCK1  256
#define NTHREAD (GRID1*BLOCK1)   // 524288 = NVEC/2 exactly

typedef float f4 __attribute__((ext_vector_type(4)));

__device__ __forceinline__ f4 ntload(const float* p) {
    return __builtin_nontemporal_load(reinterpret_cast<const f4*>(p));
}

__device__ __forceinline__ float cbrt_fast(float t) {
    // t > 0 on the taken branch; cbrt(t) = exp2(log2(t)/3) via v_log_f32/v_exp_f32
    return __builtin_amdgcn_exp2f(0.33333333333333f * __builtin_amdgcn_logf(t));
}

__device__ __forceinline__ float f_lab(float t) {
    const float T0 = 0.008856f;
    return (t > T0) ? cbrt_fast(t) : (7.787f * t + 16.0f / 116.0f);
}

__device__ __forceinline__ float3 rgb2lab_n(float r, float g, float b) {
    const float XN_INV = 1.0f / 0.950456f;
    const float ZN_INV = 1.0f / 1.088754f;
    const float T0 = 0.008856f;
    float x = (0.412453f * r + 0.35758f  * g + 0.180423f * b) * XN_INV;
    float y =  0.212671f * r + 0.71516f  * g + 0.072169f * b;
    float z = (0.019334f * r + 0.119193f * g + 0.950227f * b) * ZN_INV;
    float fx = f_lab(x);
    float fy = f_lab(y);
    float fz = f_lab(z);
    float L  = (y > T0) ? (116.0f * fy - 16.0f) : (903.3f * y);
    float a  = 500.0f * (fx - fy);
    float bb = 200.0f * (fy - fz);
    return make_float3(L * 0.01f,
                       (a  + 128.0f) * (1.0f / 255.0f),
                       (bb + 128.0f) * (1.0f / 255.0f));
}

__device__ __forceinline__ float pix_loss(float pr, float pg, float pb,
                                          float tr, float tg, float tb) {
    float3 p = rgb2lab_n(pr, pg, pb);
    float3 t = rgb2lab_n(tr, tg, tb);
    float dL = p.x - t.x;
    float da = p.y - t.y;
    float db = p.z - t.z;
    return dL * dL + da * da + db * db;
}

__device__ __forceinline__ float quad_loss(const f4& pr, const f4& pg, const f4& pb,
                                           const f4& tr, const f4& tg, const f4& tb) {
    float a;
    a  = pix_loss(pr.x, pg.x, pb.x, tr.x, tg.x, tb.x);
    a += pix_loss(pr.y, pg.y, pb.y, tr.y, tg.y, tb.y);
    a += pix_loss(pr.z, pg.z, pb.z, tr.z, tg.z, tb.z);
    a += pix_loss(pr.w, pg.w, pb.w, tr.w, tg.w, tb.w);
    return a;
}

__global__ __launch_bounds__(BLOCK1) void cc_fused(
        const float* __restrict__ pred,
        const float* __restrict__ tgt,
        float* __restrict__ part,
        unsigned* __restrict__ ticket,
        float* __restrict__ out) {
    const int t0 = blockIdx.x * BLOCK1 + threadIdx.x;   // [0, 524288)
    const int t1 = t0 + NTHREAD;                        // [524288, 1048576) — NVEC = 2*NTHREAD

    const int q0 = t0 << 2;
    const int q1 = t1 << 2;
    const size_t base0 = (size_t)(q0 >> HW_LOG2) * BSTRIDE + (q0 & (HW - 1));
    const size_t base1 = (size_t)(q1 >> HW_LOG2) * BSTRIDE + (q1 & (HW - 1));

    // Issue all 12 float4 loads up front (nt streaming hint) for max MLP.
    const f4 pr0 = ntload(pred + base0);
    const f4 pg0 = ntload(pred + base0 + CH);
    const f4 pb0 = ntload(pred + base0 + 2 * CH);
    const f4 tr0 = ntload(tgt  + base0);
    const f4 tg0 = ntload(tgt  + base0 + CH);
    const f4 tb0 = ntload(tgt  + base0 + 2 * CH);
    const f4 pr1 = ntload(pred + base1);
    const f4 pg1 = ntload(pred + base1 + CH);
    const f4 pb1 = ntload(pred + base1 + 2 * CH);
    const f4 tr1 = ntload(tgt  + base1);
    const f4 tg1 = ntload(tgt  + base1 + CH);
    const f4 tb1 = ntload(tgt  + base1 + 2 * CH);

    float acc = quad_loss(pr0, pg0, pb0, tr0, tg0, tb0)
              + quad_loss(pr1, pg1, pb1, tr1, tg1, tb1);

    // wave (64-lane) shuffle reduce
    #pragma unroll
    for (int off = 32; off > 0; off >>= 1)
        acc += __shfl_down(acc, off);

    __shared__ float smem[BLOCK1 / 64];
    __shared__ int isLast;
    const int lane = threadIdx.x & 63;
    const int wid  = threadIdx.x >> 6;
    if (lane == 0) smem[wid] = acc;
    __syncthreads();
    if (threadIdx.x == 0) {
        float s = 0.0f;
        #pragma unroll
        for (int w = 0; w < BLOCK1 / 64; ++w) s += smem[w];
        part[blockIdx.x] = s;
        __threadfence();                         // release partial
        unsigned old = atomicAdd(ticket, 1u);    // device-scope
        isLast = (old == GRID1 - 1) ? 1 : 0;
    }
    __syncthreads();

    if (isLast) {
        __threadfence();   // acquire: all 2048 partials now visible
        // fixed-assignment, fixed-tree reduction -> bit-deterministic
        float a = 0.0f;
        #pragma unroll
        for (int j = 0; j < GRID1 / BLOCK1; ++j)
            a += part[threadIdx.x + j * BLOCK1];
        #pragma unroll
        for (int off = 32; off > 0; off >>= 1)
            a += __shfl_down(a, off);
        if (lane == 0) smem[wid] = a;
        __syncthreads();
        if (threadIdx.x == 0) {
            float s = smem[0] + smem[1] + smem[2] + smem[3];
            out[0] = s * NELEM_INV;   // WEIGHT = 1.0
        }
    }
}

extern "C" void kernel_launch(void* const* d_in, const int* in_sizes, int n_in,
                              void* d_out, int out_size, void* d_ws, size_t ws_size,
                              hipStream_t stream) {
    const float* pred = (const float*)d_in[0];
    const float* tgt  = (const float*)d_in[1];
    float* out = (float*)d_out;

    unsigned* ticket = (unsigned*)d_ws;                    // 4 B counter
    float* part = (float*)((char*)d_ws + 256);             // 2048 floats, own cacheline

    (void)hipMemsetAsync(d_ws, 0, 4, stream);              // zero ticket (graph memset node)
    cc_fused<<<GRID1, BLOCK1, 0, stream>>>(pred, tgt, part, ticket, out);
}

// Round 5
// 88.995 us; speedup vs baseline: 1.3257x; 1.3257x over previous
//
#include <hip/hip_runtime.h>

// Problem constants (setup_inputs: [16, 3, 512, 512] fp32)
#define HW      262144      // 512*512 (power of two: 2^18)
#define HW_LOG2 18
#define NVEC    1048576     // 16*512*512/4  (float4-vectorized pixels)
#define CH      HW          // channel stride (elements)
#define BSTRIDE (3*HW)      // batch stride (elements)
#define NELEM_INV (1.0f / 12582912.0f)   // 1 / (16*3*512*512)

#define GRID1   2048
#define BLOCK1  256
#define NTHREAD (GRID1*BLOCK1)   // 524288 = NVEC/2 exactly

typedef float f4 __attribute__((ext_vector_type(4)));

__device__ __forceinline__ f4 vload(const float* p) {
    return *reinterpret_cast<const f4*>(p);   // plain global_load_dwordx4 (cached)
}

__device__ __forceinline__ float cbrt_fast(float t) {
    // t > 0 on the taken branch; cbrt(t) = exp2(log2(t)/3) via v_log_f32/v_exp_f32
    return __builtin_amdgcn_exp2f(0.33333333333333f * __builtin_amdgcn_logf(t));
}

__device__ __forceinline__ float f_lab(float t) {
    const float T0 = 0.008856f;
    return (t > T0) ? cbrt_fast(t) : (7.787f * t + 16.0f / 116.0f);
}

__device__ __forceinline__ float3 rgb2lab_n(float r, float g, float b) {
    const float XN_INV = 1.0f / 0.950456f;
    const float ZN_INV = 1.0f / 1.088754f;
    const float T0 = 0.008856f;
    float x = (0.412453f * r + 0.35758f  * g + 0.180423f * b) * XN_INV;
    float y =  0.212671f * r + 0.71516f  * g + 0.072169f * b;
    float z = (0.019334f * r + 0.119193f * g + 0.950227f * b) * ZN_INV;
    float fx = f_lab(x);
    float fy = f_lab(y);
    float fz = f_lab(z);
    float L  = (y > T0) ? (116.0f * fy - 16.0f) : (903.3f * y);
    float a  = 500.0f * (fx - fy);
    float bb = 200.0f * (fy - fz);
    return make_float3(L * 0.01f,
                       (a  + 128.0f) * (1.0f / 255.0f),
                       (bb + 128.0f) * (1.0f / 255.0f));
}

__device__ __forceinline__ float pix_loss(float pr, float pg, float pb,
                                          float tr, float tg, float tb) {
    float3 p = rgb2lab_n(pr, pg, pb);
    float3 t = rgb2lab_n(tr, tg, tb);
    float dL = p.x - t.x;
    float da = p.y - t.y;
    float db = p.z - t.z;
    return dL * dL + da * da + db * db;
}

__device__ __forceinline__ float quad_loss(const f4& pr, const f4& pg, const f4& pb,
                                           const f4& tr, const f4& tg, const f4& tb) {
    float a;
    a  = pix_loss(pr.x, pg.x, pb.x, tr.x, tg.x, tb.x);
    a += pix_loss(pr.y, pg.y, pb.y, tr.y, tg.y, tb.y);
    a += pix_loss(pr.z, pg.z, pb.z, tr.z, tg.z, tb.z);
    a += pix_loss(pr.w, pg.w, pb.w, tr.w, tg.w, tb.w);
    return a;
}

__global__ __launch_bounds__(BLOCK1) void cc_fused(
        const float* __restrict__ pred,
        const float* __restrict__ tgt,
        float* __restrict__ part,
        unsigned* __restrict__ ticket,
        float* __restrict__ out) {
    const int t0 = blockIdx.x * BLOCK1 + threadIdx.x;   // [0, 524288)
    const int t1 = t0 + NTHREAD;                        // [524288, 1048576) — NVEC = 2*NTHREAD

    const int q0 = t0 << 2;
    const int q1 = t1 << 2;
    const size_t base0 = (size_t)(q0 >> HW_LOG2) * BSTRIDE + (q0 & (HW - 1));
    const size_t base1 = (size_t)(q1 >> HW_LOG2) * BSTRIDE + (q1 & (HW - 1));

    // Issue all 12 float4 loads up front for max memory-level parallelism.
    const f4 pr0 = vload(pred + base0);
    const f4 pg0 = vload(pred + base0 + CH);
    const f4 pb0 = vload(pred + base0 + 2 * CH);
    const f4 tr0 = vload(tgt  + base0);
    const f4 tg0 = vload(tgt  + base0 + CH);
    const f4 tb0 = vload(tgt  + base0 + 2 * CH);
    const f4 pr1 = vload(pred + base1);
    const f4 pg1 = vload(pred + base1 + CH);
    const f4 pb1 = vload(pred + base1 + 2 * CH);
    const f4 tr1 = vload(tgt  + base1);
    const f4 tg1 = vload(tgt  + base1 + CH);
    const f4 tb1 = vload(tgt  + base1 + 2 * CH);

    float acc = quad_loss(pr0, pg0, pb0, tr0, tg0, tb0)
              + quad_loss(pr1, pg1, pb1, tr1, tg1, tb1);

    // wave (64-lane) shuffle reduce
    #pragma unroll
    for (int off = 32; off > 0; off >>= 1)
        acc += __shfl_down(acc, off);

    __shared__ float smem[BLOCK1 / 64];
    __shared__ int isLast;
    const int lane = threadIdx.x & 63;
    const int wid  = threadIdx.x >> 6;
    if (lane == 0) smem[wid] = acc;
    __syncthreads();
    if (threadIdx.x == 0) {
        float s = 0.0f;
        #pragma unroll
        for (int w = 0; w < BLOCK1 / 64; ++w) s += smem[w];
        part[blockIdx.x] = s;
        __threadfence();                         // release partial
        unsigned old = atomicAdd(ticket, 1u);    // device-scope
        isLast = (old == GRID1 - 1) ? 1 : 0;
    }
    __syncthreads();

    if (isLast) {
        __threadfence();   // acquire: all 2048 partials now visible
        // fixed-assignment, fixed-tree reduction -> bit-deterministic
        float a = 0.0f;
        #pragma unroll
        for (int j = 0; j < GRID1 / BLOCK1; ++j)
            a += part[threadIdx.x + j * BLOCK1];
        #pragma unroll
        for (int off = 32; off > 0; off >>= 1)
            a += __shfl_down(a, off);
        if (lane == 0) smem[wid] = a;
        __syncthreads();
        if (threadIdx.x == 0) {
            float s = smem[0] + smem[1] + smem[2] + smem[3];
            out[0] = s * NELEM_INV;   // WEIGHT = 1.0
        }
    }
}

extern "C" void kernel_launch(void* const* d_in, const int* in_sizes, int n_in,
                              void* d_out, int out_size, void* d_ws, size_t ws_size,
                              hipStream_t stream) {
    const float* pred = (const float*)d_in[0];
    const float* tgt  = (const float*)d_in[1];
    float* out = (float*)d_out;

    unsigned* ticket = (unsigned*)d_ws;                    // 4 B counter
    float* part = (float*)((char*)d_ws + 256);             // 2048 floats, own cacheline

    (void)hipMemsetAsync(d_ws, 0, 4, stream);              // zero ticket (graph memset node)
    cc_fused<<<GRID1, BLOCK1, 0, stream>>>(pred, tgt, part, ticket, out);
}

// Round 6
// 26.846 us; speedup vs baseline: 4.3948x; 3.3150x over previous
//
#include <hip/hip_runtime.h>

// Problem constants (setup_inputs: [16, 3, 512, 512] fp32)
#define HW      262144      // 512*512 (power of two: 2^18)
#define HW_LOG2 18
#define NVEC    1048576     // 16*512*512/4  (float4-vectorized pixels)
#define CH      HW          // channel stride (elements)
#define BSTRIDE (3*HW)      // batch stride (elements)
#define NELEM_INV (1.0f / 12582912.0f)   // 1 / (16*3*512*512)

#define GRID1   2048
#define BLOCK1  256
#define NTHREAD (GRID1*BLOCK1)   // 524288 = NVEC/2 exactly

typedef float f4 __attribute__((ext_vector_type(4)));

__device__ __forceinline__ f4 vload(const float* p) {
    return *reinterpret_cast<const f4*>(p);   // global_load_dwordx4 (cached)
}

__device__ __forceinline__ float cbrt_fast(float t) {
    // t > 0 on the taken branch; cbrt(t) = exp2(log2(t)/3) via v_log_f32/v_exp_f32
    return __builtin_amdgcn_exp2f(0.33333333333333f * __builtin_amdgcn_logf(t));
}

__device__ __forceinline__ float f_lab(float t) {
    const float T0 = 0.008856f;
    return (t > T0) ? cbrt_fast(t) : (7.787f * t + 16.0f / 116.0f);
}

__device__ __forceinline__ float3 rgb2lab_n(float r, float g, float b) {
    const float XN_INV = 1.0f / 0.950456f;
    const float ZN_INV = 1.0f / 1.088754f;
    const float T0 = 0.008856f;
    float x = (0.412453f * r + 0.35758f  * g + 0.180423f * b) * XN_INV;
    float y =  0.212671f * r + 0.71516f  * g + 0.072169f * b;
    float z = (0.019334f * r + 0.119193f * g + 0.950227f * b) * ZN_INV;
    float fx = f_lab(x);
    float fy = f_lab(y);
    float fz = f_lab(z);
    float L  = (y > T0) ? (116.0f * fy - 16.0f) : (903.3f * y);
    float a  = 500.0f * (fx - fy);
    float bb = 200.0f * (fy - fz);
    return make_float3(L * 0.01f,
                       (a  + 128.0f) * (1.0f / 255.0f),
                       (bb + 128.0f) * (1.0f / 255.0f));
}

__device__ __forceinline__ float pix_loss(float pr, float pg, float pb,
                                          float tr, float tg, float tb) {
    float3 p = rgb2lab_n(pr, pg, pb);
    float3 t = rgb2lab_n(tr, tg, tb);
    float dL = p.x - t.x;
    float da = p.y - t.y;
    float db = p.z - t.z;
    return dL * dL + da * da + db * db;
}

__device__ __forceinline__ float quad_loss(const f4& pr, const f4& pg, const f4& pb,
                                           const f4& tr, const f4& tg, const f4& tb) {
    float a;
    a  = pix_loss(pr.x, pg.x, pb.x, tr.x, tg.x, tb.x);
    a += pix_loss(pr.y, pg.y, pb.y, tr.y, tg.y, tb.y);
    a += pix_loss(pr.z, pg.z, pb.z, tr.z, tg.z, tb.z);
    a += pix_loss(pr.w, pg.w, pb.w, tr.w, tg.w, tb.w);
    return a;
}

// min-waves/EU = 1: free the register allocator so all 12 dwordx4 results
// can be live at once (R5's VGPR=32 allocation serialized the loads).
__global__ __launch_bounds__(BLOCK1, 1) void cc_partial(
        const float* __restrict__ pred,
        const float* __restrict__ tgt,
        float* __restrict__ part) {
    const int t0 = blockIdx.x * BLOCK1 + threadIdx.x;   // [0, 524288)
    const int t1 = t0 + NTHREAD;                        // [524288, 1048576)

    const int q0 = t0 << 2;
    const int q1 = t1 << 2;
    const size_t base0 = (size_t)(q0 >> HW_LOG2) * BSTRIDE + (q0 & (HW - 1));
    const size_t base1 = (size_t)(q1 >> HW_LOG2) * BSTRIDE + (q1 & (HW - 1));

    // Issue all 12 float4 loads up front for max memory-level parallelism.
    const f4 pr0 = vload(pred + base0);
    const f4 pg0 = vload(pred + base0 + CH);
    const f4 pb0 = vload(pred + base0 + 2 * CH);
    const f4 tr0 = vload(tgt  + base0);
    const f4 tg0 = vload(tgt  + base0 + CH);
    const f4 tb0 = vload(tgt  + base0 + 2 * CH);
    const f4 pr1 = vload(pred + base1);
    const f4 pg1 = vload(pred + base1 + CH);
    const f4 pb1 = vload(pred + base1 + 2 * CH);
    const f4 tr1 = vload(tgt  + base1);
    const f4 tg1 = vload(tgt  + base1 + CH);
    const f4 tb1 = vload(tgt  + base1 + 2 * CH);

    float acc = quad_loss(pr0, pg0, pb0, tr0, tg0, tb0)
              + quad_loss(pr1, pg1, pb1, tr1, tg1, tb1);

    // wave (64-lane) shuffle reduce
    #pragma unroll
    for (int off = 32; off > 0; off >>= 1)
        acc += __shfl_down(acc, off);

    __shared__ float smem[BLOCK1 / 64];
    const int lane = threadIdx.x & 63;
    const int wid  = threadIdx.x >> 6;
    if (lane == 0) smem[wid] = acc;
    __syncthreads();
    if (threadIdx.x == 0) {
        float s = 0.0f;
        #pragma unroll
        for (int w = 0; w < BLOCK1 / 64; ++w) s += smem[w];
        part[blockIdx.x] = s;
    }
}

__global__ __launch_bounds__(256) void cc_final(
        const float* __restrict__ part,
        float* __restrict__ out,
        int nparts) {
    float acc = 0.0f;
    for (int i = threadIdx.x; i < nparts; i += 256)
        acc += part[i];

    #pragma unroll
    for (int off = 32; off > 0; off >>= 1)
        acc += __shfl_down(acc, off);

    __shared__ float smem[4];
    const int lane = threadIdx.x & 63;
    const int wid  = threadIdx.x >> 6;
    if (lane == 0) smem[wid] = acc;
    __syncthreads();
    if (threadIdx.x == 0) {
        float s = smem[0] + smem[1] + smem[2] + smem[3];
        out[0] = s * NELEM_INV;   // WEIGHT = 1.0
    }
}

extern "C" void kernel_launch(void* const* d_in, const int* in_sizes, int n_in,
                              void* d_out, int out_size, void* d_ws, size_t ws_size,
                              hipStream_t stream) {
    const float* pred = (const float*)d_in[0];
    const float* tgt  = (const float*)d_in[1];
    float* out  = (float*)d_out;
    float* part = (float*)d_ws;   // GRID1 floats = 8 KiB scratch

    cc_partial<<<GRID1, BLOCK1, 0, stream>>>(pred, tgt, part);
    cc_final<<<1, 256, 0, stream>>>(part, out, GRID1);
}